// Round 1
// baseline (566.990 us; speedup 1.0000x reference)
//
#include <hip/hip_runtime.h>

#define NF 64  // feature width (F_IN == F_LAT == F_OUT == 64)

// ---------------------------------------------------------------------------
// Degree histogram: one thread per edge, two int atomics.
__global__ __launch_bounds__(256) void degree_kernel(
    const int* __restrict__ src, const int* __restrict__ dst,
    int* __restrict__ deg_out, int* __restrict__ deg_in, int nE) {
  int e = blockIdx.x * blockDim.x + threadIdx.x;
  if (e >= nE) return;
  atomicAdd(&deg_out[src[e]], 1);
  atomicAdd(&deg_in[dst[e]], 1);
}

// deg -> deg^{-1/2} (0 stays 0)
__global__ __launch_bounds__(256) void isqrt_kernel(
    const int* __restrict__ deg_out, const int* __restrict__ deg_in,
    float* __restrict__ so, float* __restrict__ si, int n) {
  int i = blockIdx.x * blockDim.x + threadIdx.x;
  if (i >= n) return;
  int dO = deg_out[i];
  int dI = deg_in[i];
  so[i] = dO > 0 ? rsqrtf((float)dO) : 0.f;
  si[i] = dI > 0 ? rsqrtf((float)dI) : 0.f;
}

// ---------------------------------------------------------------------------
// Fused GEMM: H[r][j] = sum_k T(A[r][k]) * W[k][j]
//   MODE 0: T = A[r][k] * so[r]                          (layer-1 input)
//   MODE 1: T = relu(A[r][k]*si[r] + b[k]) * so[r]       (layer-1 epilogue
//                                                          fused into layer-2)
// Block: 256 threads, 32 rows per block. W (16 KB) + scaled A-rows (8 KB)
// staged in LDS. Inner loop: Xl broadcast (wave-uniform) × Wl (64 consecutive
// floats -> 2-way bank alias, free on gfx950).
template <int MODE>
__global__ __launch_bounds__(256) void gemm_scaled(
    const float* __restrict__ A, const float* __restrict__ so,
    const float* __restrict__ si, const float* __restrict__ bias,
    const float* __restrict__ W, float* __restrict__ H, int n) {
  __shared__ float Wl[NF * NF];
  __shared__ float Xl[32 * NF];
  const int t = threadIdx.x;

  // Stage W: 4096 floats / 256 threads = 16 each (coalesced).
  #pragma unroll
  for (int i = 0; i < 16; ++i) Wl[t + 256 * i] = W[t + 256 * i];

  const int row0 = blockIdx.x * 32;
  // Stage 32 scaled input rows: 2048 floats / 256 threads = 8 each.
  #pragma unroll
  for (int i = 0; i < 8; ++i) {
    int idx = t + 256 * i;       // [0, 2048)
    int r = row0 + (idx >> 6);
    int c = idx & 63;
    float v = 0.f;
    if (r < n) {
      float a = A[r * NF + c];
      if (MODE == 0) {
        v = a * so[r];
      } else {
        v = fmaxf(fmaf(a, si[r], bias[c]), 0.f) * so[r];
      }
    }
    Xl[idx] = v;
  }
  __syncthreads();

  const int j = t & 63;        // output column = lane
  const int rg = t >> 6;       // wave id 0..3 -> row group
  #pragma unroll
  for (int i = 0; i < 8; ++i) {
    int lr = rg + i * 4;       // local row 0..31
    int r = row0 + lr;
    if (r >= n) continue;
    float acc = 0.f;
    #pragma unroll
    for (int k = 0; k < NF; ++k) acc = fmaf(Xl[lr * NF + k], Wl[k * NF + j], acc);
    H[r * NF + j] = acc;
  }
}

// ---------------------------------------------------------------------------
// Edge scatter: one wave per edge, lane = feature. Coalesced 256B gather from
// H[src], coalesced 256B float atomicAdd into Agg[dst].
__global__ __launch_bounds__(256) void scatter_add(
    const float* __restrict__ H, const int* __restrict__ src,
    const int* __restrict__ dst, float* __restrict__ Agg, int nE) {
  int e = blockIdx.x * 4 + (threadIdx.x >> 6);
  if (e >= nE) return;
  int lane = threadIdx.x & 63;
  int s = src[e];
  int d = dst[e];
  atomicAdd(&Agg[d * NF + lane], H[s * NF + lane]);
}

// out[i][j] = Agg[i][j] * si[i] + b2[j]
__global__ __launch_bounds__(256) void finalize_kernel(
    const float* __restrict__ Agg, const float* __restrict__ si,
    const float* __restrict__ b2, float* __restrict__ out, int n) {
  int idx = blockIdx.x * blockDim.x + threadIdx.x;
  if (idx >= n * NF) return;
  int r = idx >> 6;
  int c = idx & 63;
  out[idx] = fmaf(Agg[idx], si[r], b2[c]);
}

// ---------------------------------------------------------------------------
extern "C" void kernel_launch(void* const* d_in, const int* in_sizes, int n_in,
                              void* d_out, int out_size, void* d_ws, size_t ws_size,
                              hipStream_t stream) {
  const float* x  = (const float*)d_in[0];
  const float* W1 = (const float*)d_in[1];
  const float* b1 = (const float*)d_in[2];
  const float* W2 = (const float*)d_in[3];
  const float* b2 = (const float*)d_in[4];
  const int* src  = (const int*)d_in[5];
  const int* dst  = (const int*)d_in[6];
  float* out = (float*)d_out;

  const int N = in_sizes[0] / NF;   // 50000
  const int E = in_sizes[5];        // 800000

  // Workspace layout (256B-aligned segments), total ~26.4 MB.
  char* ws = (char*)d_ws;
  size_t p = 0;
  auto alloc = [&](size_t bytes) -> void* {
    void* r = ws + p;
    p = (p + bytes + 255) & ~(size_t)255;
    return r;
  };
  int*   deg_out_i = (int*)  alloc((size_t)N * 4);
  int*   deg_in_i  = (int*)  alloc((size_t)N * 4);
  float* so        = (float*)alloc((size_t)N * 4);
  float* si        = (float*)alloc((size_t)N * 4);
  float* h         = (float*)alloc((size_t)N * NF * 4);
  float* agg       = (float*)alloc((size_t)N * NF * 4);

  // 1. degrees
  hipMemsetAsync(deg_out_i, 0, (size_t)N * 4, stream);
  hipMemsetAsync(deg_in_i, 0, (size_t)N * 4, stream);
  degree_kernel<<<(E + 255) / 256, 256, 0, stream>>>(src, dst, deg_out_i, deg_in_i, E);
  isqrt_kernel<<<(N + 255) / 256, 256, 0, stream>>>(deg_out_i, deg_in_i, so, si, N);

  const int gemm_grid = (N + 31) / 32;

  // 2. layer 1: h = (x * so) @ W1
  gemm_scaled<0><<<gemm_grid, 256, 0, stream>>>(x, so, nullptr, nullptr, W1, h, N);

  // 3. agg = scatter_sum(h[src] -> dst)
  hipMemsetAsync(agg, 0, (size_t)N * NF * 4, stream);
  scatter_add<<<(E + 3) / 4, 256, 0, stream>>>(h, src, dst, agg, E);

  // 4. layer 2: h = (relu(agg*si + b1) * so) @ W2
  gemm_scaled<1><<<gemm_grid, 256, 0, stream>>>(agg, so, si, b1, W2, h, N);

  // 5. agg = scatter_sum(h[src] -> dst)
  hipMemsetAsync(agg, 0, (size_t)N * NF * 4, stream);
  scatter_add<<<(E + 3) / 4, 256, 0, stream>>>(h, src, dst, agg, E);

  // 6. out = agg * si + b2
  finalize_kernel<<<(N * NF + 255) / 256, 256, 0, stream>>>(agg, si, b2, out, N);
}

// Round 2
// 350.971 us; speedup vs baseline: 1.6155x; 1.6155x over previous
//
#include <hip/hip_runtime.h>

#define NF 64  // feature width (F_IN == F_LAT == F_OUT == 64)

// ---------------------------------------------------------------------------
// Degree histogram: one thread per edge, two int atomics.
__global__ __launch_bounds__(256) void degree_kernel(
    const int* __restrict__ src, const int* __restrict__ dst,
    int* __restrict__ deg_out, int* __restrict__ deg_in, int nE) {
  int e = blockIdx.x * blockDim.x + threadIdx.x;
  if (e >= nE) return;
  atomicAdd(&deg_out[src[e]], 1);
  atomicAdd(&deg_in[dst[e]], 1);
}

// deg -> deg^{-1/2} (0 stays 0)
__global__ __launch_bounds__(256) void isqrt_kernel(
    const int* __restrict__ deg_out, const int* __restrict__ deg_in,
    float* __restrict__ so, float* __restrict__ si, int n) {
  int i = blockIdx.x * blockDim.x + threadIdx.x;
  if (i >= n) return;
  int dO = deg_out[i];
  int dI = deg_in[i];
  so[i] = dO > 0 ? rsqrtf((float)dO) : 0.f;
  si[i] = dI > 0 ? rsqrtf((float)dI) : 0.f;
}

// ---------------------------------------------------------------------------
// Exclusive scan of deg_in -> row_start (CSR by dst). 3-phase hierarchical.
__global__ __launch_bounds__(256) void scan1_kernel(
    const int* __restrict__ deg, int* __restrict__ lscan,
    int* __restrict__ bsum, int n) {
  __shared__ int s[256];
  int tid = threadIdx.x;
  int i = blockIdx.x * 256 + tid;
  int v = (i < n) ? deg[i] : 0;
  s[tid] = v;
  __syncthreads();
  #pragma unroll
  for (int off = 1; off < 256; off <<= 1) {
    int t2 = (tid >= off) ? s[tid - off] : 0;
    __syncthreads();
    s[tid] += t2;
    __syncthreads();
  }
  if (i < n) lscan[i] = s[tid] - v;  // exclusive within block
  if (tid == 255) bsum[blockIdx.x] = s[255];
}

__global__ __launch_bounds__(256) void scan2_kernel(int* __restrict__ bsum, int nb) {
  __shared__ int s[256];
  int tid = threadIdx.x;
  int v = (tid < nb) ? bsum[tid] : 0;
  s[tid] = v;
  __syncthreads();
  #pragma unroll
  for (int off = 1; off < 256; off <<= 1) {
    int t2 = (tid >= off) ? s[tid - off] : 0;
    __syncthreads();
    s[tid] += t2;
    __syncthreads();
  }
  if (tid < nb) bsum[tid] = s[tid] - v;  // exclusive across blocks
}

__global__ __launch_bounds__(256) void scan3_kernel(
    const int* __restrict__ lscan, const int* __restrict__ bsum,
    int* __restrict__ row_start, int* __restrict__ cursor, int n, int nE) {
  int i = blockIdx.x * 256 + threadIdx.x;
  if (i == 0) row_start[n] = nE;
  if (i < n) {
    int v = lscan[i] + bsum[blockIdx.x];
    row_start[i] = v;
    cursor[i] = v;
  }
}

// Counting-sort edges by dst: sorted_src[bucket(dst)] = src.
__global__ __launch_bounds__(256) void bucket_kernel(
    const int* __restrict__ src, const int* __restrict__ dst,
    int* __restrict__ cursor, int* __restrict__ sorted_src, int nE) {
  int e = blockIdx.x * blockDim.x + threadIdx.x;
  if (e >= nE) return;
  int pos = atomicAdd(&cursor[dst[e]], 1);
  sorted_src[pos] = src[e];
}

// ---------------------------------------------------------------------------
// Register-blocked GEMM: H[r][j] = sum_k T(A[r][k]) * W[k][j]
//   MODE 0: T = A[r][k] * so[r]   (layer-1 pre-scale)
//   MODE 1: T = A[r][k]           (layer-2: scaling already folded into A)
// 64x64 output tile per 256-thread block; each thread owns a 4x4 register
// tile. A staged in LDS padded to stride 68 (keeps float4 16B alignment,
// <=2-way bank alias). 8 ds_read_b128 per 64 FMAs.
template <int MODE>
__global__ __launch_bounds__(256) void gemm64(
    const float* __restrict__ A, const float* __restrict__ so,
    const float* __restrict__ W, float* __restrict__ H, int n) {
  __shared__ float Wl[NF * NF];       // 16 KB, row-major [k][j]
  __shared__ float Xl[NF * 68];       // 17 KB, row-major [r][k], stride 68
  const int t = threadIdx.x;

  #pragma unroll
  for (int i = 0; i < 16; ++i) Wl[t + 256 * i] = W[t + 256 * i];

  const int row0 = blockIdx.x * 64;
  #pragma unroll
  for (int i = 0; i < 16; ++i) {
    int idx = t + 256 * i;            // [0, 4096)
    int r = idx >> 6;                 // wave-uniform
    int c = idx & 63;                 // = lane
    int gr = row0 + r;
    float v = 0.f;
    if (gr < n) {
      v = A[(size_t)gr * NF + c];
      if (MODE == 0) v *= so[gr];
    }
    Xl[r * 68 + c] = v;
  }
  __syncthreads();

  const int tx = t & 15;              // col group: cols tx*4..+3
  const int ty = t >> 4;              // row group: rows ty*4..+3
  float4 acc0 = {0, 0, 0, 0}, acc1 = {0, 0, 0, 0};
  float4 acc2 = {0, 0, 0, 0}, acc3 = {0, 0, 0, 0};

  #pragma unroll
  for (int k4 = 0; k4 < 16; ++k4) {
    const float4 a0 = *(const float4*)&Xl[(ty * 4 + 0) * 68 + k4 * 4];
    const float4 a1 = *(const float4*)&Xl[(ty * 4 + 1) * 68 + k4 * 4];
    const float4 a2 = *(const float4*)&Xl[(ty * 4 + 2) * 68 + k4 * 4];
    const float4 a3 = *(const float4*)&Xl[(ty * 4 + 3) * 68 + k4 * 4];
    const float4 b0 = *(const float4*)&Wl[(k4 * 4 + 0) * NF + tx * 4];
    const float4 b1 = *(const float4*)&Wl[(k4 * 4 + 1) * NF + tx * 4];
    const float4 b2 = *(const float4*)&Wl[(k4 * 4 + 2) * NF + tx * 4];
    const float4 b3 = *(const float4*)&Wl[(k4 * 4 + 3) * NF + tx * 4];

#define FMA4(ACC, AV, BV)                         \
    ACC.x = fmaf(AV, BV.x, ACC.x);                \
    ACC.y = fmaf(AV, BV.y, ACC.y);                \
    ACC.z = fmaf(AV, BV.z, ACC.z);                \
    ACC.w = fmaf(AV, BV.w, ACC.w);
    FMA4(acc0, a0.x, b0) FMA4(acc0, a0.y, b1) FMA4(acc0, a0.z, b2) FMA4(acc0, a0.w, b3)
    FMA4(acc1, a1.x, b0) FMA4(acc1, a1.y, b1) FMA4(acc1, a1.z, b2) FMA4(acc1, a1.w, b3)
    FMA4(acc2, a2.x, b0) FMA4(acc2, a2.y, b1) FMA4(acc2, a2.z, b2) FMA4(acc2, a2.w, b3)
    FMA4(acc3, a3.x, b0) FMA4(acc3, a3.y, b1) FMA4(acc3, a3.z, b2) FMA4(acc3, a3.w, b3)
#undef FMA4
  }

  const int col = tx * 4;
  #pragma unroll
  for (int i = 0; i < 4; ++i) {
    int gr = row0 + ty * 4 + i;
    if (gr >= n) continue;
    float4 v = (i == 0) ? acc0 : (i == 1) ? acc1 : (i == 2) ? acc2 : acc3;
    *(float4*)&H[(size_t)gr * NF + col] = v;
  }
}

// ---------------------------------------------------------------------------
// CSR segment-sum: one wave per dst node, lane = feature. Gathers H[src] rows
// (coalesced 256B each) and accumulates in registers; single write per node.
//   MODE 0 (inter-layer): out = relu(sum*si + b) * so   (feeds layer-2 GEMM)
//   MODE 1 (final):       out = sum*si + b
template <int MODE>
__global__ __launch_bounds__(256) void agg_kernel(
    const float* __restrict__ H, const int* __restrict__ row_start,
    const int* __restrict__ srcs, const float* __restrict__ si,
    const float* __restrict__ so, const float* __restrict__ bias,
    float* __restrict__ out, int n) {
  int node = blockIdx.x * 4 + (threadIdx.x >> 6);
  if (node >= n) return;
  int lane = threadIdx.x & 63;
  int beg = row_start[node];
  int end = row_start[node + 1];

  float s0 = 0.f, s1 = 0.f, s2 = 0.f, s3 = 0.f;
  int e = beg;
  for (; e + 4 <= end; e += 4) {
    int i0 = srcs[e + 0];
    int i1 = srcs[e + 1];
    int i2 = srcs[e + 2];
    int i3 = srcs[e + 3];
    s0 += H[(size_t)i0 * NF + lane];
    s1 += H[(size_t)i1 * NF + lane];
    s2 += H[(size_t)i2 * NF + lane];
    s3 += H[(size_t)i3 * NF + lane];
  }
  for (; e < end; ++e) s0 += H[(size_t)srcs[e] * NF + lane];
  float sum = (s0 + s1) + (s2 + s3);

  float r;
  if (MODE == 0) {
    r = fmaxf(fmaf(sum, si[node], bias[lane]), 0.f) * so[node];
  } else {
    r = fmaf(sum, si[node], bias[lane]);
  }
  out[(size_t)node * NF + lane] = r;
}

// ---------------------------------------------------------------------------
extern "C" void kernel_launch(void* const* d_in, const int* in_sizes, int n_in,
                              void* d_out, int out_size, void* d_ws, size_t ws_size,
                              hipStream_t stream) {
  const float* x  = (const float*)d_in[0];
  const float* W1 = (const float*)d_in[1];
  const float* b1 = (const float*)d_in[2];
  const float* W2 = (const float*)d_in[3];
  const float* b2 = (const float*)d_in[4];
  const int* src  = (const int*)d_in[5];
  const int* dst  = (const int*)d_in[6];
  float* out = (float*)d_out;

  const int N = in_sizes[0] / NF;   // 50000
  const int E = in_sizes[5];        // 800000
  const int NB = (N + 255) / 256;   // scan blocks (196 <= 256)

  // Workspace layout (256B-aligned segments), ~30 MB total.
  char* ws = (char*)d_ws;
  size_t p = 0;
  auto alloc = [&](size_t bytes) -> void* {
    void* r = ws + p;
    p = (p + bytes + 255) & ~(size_t)255;
    return r;
  };
  int*   deg_out_i  = (int*)  alloc((size_t)N * 4);       // reused as lscan
  int*   deg_in_i   = (int*)  alloc((size_t)N * 4);       // reused as cursor
  float* so         = (float*)alloc((size_t)N * 4);
  float* si         = (float*)alloc((size_t)N * 4);
  int*   row_start  = (int*)  alloc((size_t)(N + 1) * 4);
  int*   bsum       = (int*)  alloc((size_t)NB * 4);
  int*   sorted_src = (int*)  alloc((size_t)E * 4);
  float* h          = (float*)alloc((size_t)N * NF * 4);
  float* tbuf       = (float*)alloc((size_t)N * NF * 4);

  // 1. degrees + normalization
  hipMemsetAsync(deg_out_i, 0, (size_t)N * 4, stream);
  hipMemsetAsync(deg_in_i, 0, (size_t)N * 4, stream);
  degree_kernel<<<(E + 255) / 256, 256, 0, stream>>>(src, dst, deg_out_i, deg_in_i, E);
  isqrt_kernel<<<(N + 255) / 256, 256, 0, stream>>>(deg_out_i, deg_in_i, so, si, N);

  // 2. CSR by dst (counting sort). lscan aliases deg_out_i (dead after isqrt);
  //    cursor aliases deg_in_i (dead after scan1).
  int* lscan  = deg_out_i;
  int* cursor = deg_in_i;
  scan1_kernel<<<NB, 256, 0, stream>>>(deg_in_i, lscan, bsum, N);
  scan2_kernel<<<1, 256, 0, stream>>>(bsum, NB);
  scan3_kernel<<<NB, 256, 0, stream>>>(lscan, bsum, row_start, cursor, N, E);
  bucket_kernel<<<(E + 255) / 256, 256, 0, stream>>>(src, dst, cursor, sorted_src, E);

  const int ggrid = (N + 63) / 64;
  const int agrid = (N + 3) / 4;

  // 3. layer 1: h = (x*so) @ W1 ; t = relu(segsum(h)*si + b1) * so
  gemm64<0><<<ggrid, 256, 0, stream>>>(x, so, W1, h, N);
  agg_kernel<0><<<agrid, 256, 0, stream>>>(h, row_start, sorted_src, si, so, b1, tbuf, N);

  // 4. layer 2: h = t @ W2 ; out = segsum(h)*si + b2
  gemm64<1><<<ggrid, 256, 0, stream>>>(tbuf, nullptr, W2, h, N);
  agg_kernel<1><<<agrid, 256, 0, stream>>>(h, row_start, sorted_src, si, nullptr, b2, out, N);
}

// Round 3
// 298.776 us; speedup vs baseline: 1.8977x; 1.1747x over previous
//
#include <hip/hip_runtime.h>

#define NF 64  // feature width (F_IN == F_LAT == F_OUT == 64)

// ---------------------------------------------------------------------------
// Degree histogram + dst-ticket: one thread per edge.
// ticket[e] = arrival index of edge e within its dst bucket (from the atomic's
// returned old value) -> later sorted position = row_start[dst] + ticket,
// eliminating the counting-sort cursor atomics.
__global__ __launch_bounds__(256) void edge_kernel(
    const int* __restrict__ src, const int* __restrict__ dst,
    int* __restrict__ deg_out, int* __restrict__ deg_in,
    int* __restrict__ ticket, int nE) {
  int e = blockIdx.x * blockDim.x + threadIdx.x;
  if (e >= nE) return;
  int t = atomicAdd(&deg_in[dst[e]], 1);
  ticket[e] = t;
  atomicAdd(&deg_out[src[e]], 1);
}

// ---------------------------------------------------------------------------
// Exclusive scan of deg_in -> row_start (CSR by dst). 3-phase hierarchical.
__global__ __launch_bounds__(256) void scan1_kernel(
    const int* __restrict__ deg, int* __restrict__ lscan,
    int* __restrict__ bsum, int n) {
  __shared__ int s[256];
  int tid = threadIdx.x;
  int i = blockIdx.x * 256 + tid;
  int v = (i < n) ? deg[i] : 0;
  s[tid] = v;
  __syncthreads();
  #pragma unroll
  for (int off = 1; off < 256; off <<= 1) {
    int t2 = (tid >= off) ? s[tid - off] : 0;
    __syncthreads();
    s[tid] += t2;
    __syncthreads();
  }
  if (i < n) lscan[i] = s[tid] - v;  // exclusive within block
  if (tid == 255) bsum[blockIdx.x] = s[255];
}

__global__ __launch_bounds__(256) void scan2_kernel(int* __restrict__ bsum, int nb) {
  __shared__ int s[256];
  int tid = threadIdx.x;
  int v = (tid < nb) ? bsum[tid] : 0;
  s[tid] = v;
  __syncthreads();
  #pragma unroll
  for (int off = 1; off < 256; off <<= 1) {
    int t2 = (tid >= off) ? s[tid - off] : 0;
    __syncthreads();
    s[tid] += t2;
    __syncthreads();
  }
  if (tid < nb) bsum[tid] = s[tid] - v;  // exclusive across blocks
}

// Finalize row_start and compute deg^{-1/2} factors (isqrt fused here).
__global__ __launch_bounds__(256) void scan3_kernel(
    const int* __restrict__ lscan, const int* __restrict__ bsum,
    const int* __restrict__ deg_out, const int* __restrict__ deg_in,
    int* __restrict__ row_start, float* __restrict__ so, float* __restrict__ si,
    int n, int nE) {
  int i = blockIdx.x * 256 + threadIdx.x;
  if (i == 0) row_start[n] = nE;
  if (i < n) {
    row_start[i] = lscan[i] + bsum[blockIdx.x];
    int dO = deg_out[i];
    int dI = deg_in[i];
    so[i] = dO > 0 ? rsqrtf((float)dO) : 0.f;
    si[i] = dI > 0 ? rsqrtf((float)dI) : 0.f;
  }
}

// Counting-sort placement, atomic-free: pos = row_start[dst] + ticket.
__global__ __launch_bounds__(256) void place_kernel(
    const int* __restrict__ src, const int* __restrict__ dst,
    const int* __restrict__ ticket, const int* __restrict__ row_start,
    int* __restrict__ sorted_src, int nE) {
  int e = blockIdx.x * blockDim.x + threadIdx.x;
  if (e >= nE) return;
  int d = dst[e];
  sorted_src[row_start[d] + ticket[e]] = src[e];
}

// ---------------------------------------------------------------------------
// Register-blocked GEMM: H[r][j] = sum_k T(A[r][k]) * W[k][j]
//   MODE 0: T = A[r][k] * so[r]   (layer-1 pre-scale)
//   MODE 1: T = A[r][k]           (layer-2: scaling already folded into A)
template <int MODE>
__global__ __launch_bounds__(256) void gemm64(
    const float* __restrict__ A, const float* __restrict__ so,
    const float* __restrict__ W, float* __restrict__ H, int n) {
  __shared__ float Wl[NF * NF];       // 16 KB, row-major [k][j]
  __shared__ float Xl[NF * 68];       // 17 KB, row-major [r][k], stride 68
  const int t = threadIdx.x;

  #pragma unroll
  for (int i = 0; i < 16; ++i) Wl[t + 256 * i] = W[t + 256 * i];

  const int row0 = blockIdx.x * 64;
  #pragma unroll
  for (int i = 0; i < 16; ++i) {
    int idx = t + 256 * i;            // [0, 4096)
    int r = idx >> 6;
    int c = idx & 63;
    int gr = row0 + r;
    float v = 0.f;
    if (gr < n) {
      v = A[(size_t)gr * NF + c];
      if (MODE == 0) v *= so[gr];
    }
    Xl[r * 68 + c] = v;
  }
  __syncthreads();

  const int tx = t & 15;              // col group: cols tx*4..+3
  const int ty = t >> 4;              // row group: rows ty*4..+3
  float4 acc0 = {0, 0, 0, 0}, acc1 = {0, 0, 0, 0};
  float4 acc2 = {0, 0, 0, 0}, acc3 = {0, 0, 0, 0};

  #pragma unroll
  for (int k4 = 0; k4 < 16; ++k4) {
    const float4 a0 = *(const float4*)&Xl[(ty * 4 + 0) * 68 + k4 * 4];
    const float4 a1 = *(const float4*)&Xl[(ty * 4 + 1) * 68 + k4 * 4];
    const float4 a2 = *(const float4*)&Xl[(ty * 4 + 2) * 68 + k4 * 4];
    const float4 a3 = *(const float4*)&Xl[(ty * 4 + 3) * 68 + k4 * 4];
    const float4 b0 = *(const float4*)&Wl[(k4 * 4 + 0) * NF + tx * 4];
    const float4 b1 = *(const float4*)&Wl[(k4 * 4 + 1) * NF + tx * 4];
    const float4 b2 = *(const float4*)&Wl[(k4 * 4 + 2) * NF + tx * 4];
    const float4 b3 = *(const float4*)&Wl[(k4 * 4 + 3) * NF + tx * 4];

#define FMA4(ACC, AV, BV)                         \
    ACC.x = fmaf(AV, BV.x, ACC.x);                \
    ACC.y = fmaf(AV, BV.y, ACC.y);                \
    ACC.z = fmaf(AV, BV.z, ACC.z);                \
    ACC.w = fmaf(AV, BV.w, ACC.w);
    FMA4(acc0, a0.x, b0) FMA4(acc0, a0.y, b1) FMA4(acc0, a0.z, b2) FMA4(acc0, a0.w, b3)
    FMA4(acc1, a1.x, b0) FMA4(acc1, a1.y, b1) FMA4(acc1, a1.z, b2) FMA4(acc1, a1.w, b3)
    FMA4(acc2, a2.x, b0) FMA4(acc2, a2.y, b1) FMA4(acc2, a2.z, b2) FMA4(acc2, a2.w, b3)
    FMA4(acc3, a3.x, b0) FMA4(acc3, a3.y, b1) FMA4(acc3, a3.z, b2) FMA4(acc3, a3.w, b3)
#undef FMA4
  }

  const int col = tx * 4;
  #pragma unroll
  for (int i = 0; i < 4; ++i) {
    int gr = row0 + ty * 4 + i;
    if (gr >= n) continue;
    float4 v = (i == 0) ? acc0 : (i == 1) ? acc1 : (i == 2) ? acc2 : acc3;
    *(float4*)&H[(size_t)gr * NF + col] = v;
  }
}

// ---------------------------------------------------------------------------
// CSR segment-sum, 4 source rows per VMEM instruction:
// lane group g = lane>>4 handles row srcs[e+g]; each lane loads float4 (16B),
// so one instruction gathers 4 full 256B rows. Unrolled x2 -> 8 rows in
// flight per wave. Cross-group butterfly (xor 16, 32) merges partials.
//   MODE 0 (inter-layer): out = relu(sum*si + b) * so
//   MODE 1 (final):       out = sum*si + b
template <int MODE>
__global__ __launch_bounds__(256) void agg_kernel(
    const float* __restrict__ H, const int* __restrict__ row_start,
    const int* __restrict__ srcs, const float* __restrict__ si,
    const float* __restrict__ so, const float* __restrict__ bias,
    float* __restrict__ out, int n) {
  int node = blockIdx.x * 4 + (threadIdx.x >> 6);
  if (node >= n) return;
  const int lane = threadIdx.x & 63;
  const int g = lane >> 4;        // row group 0..3
  const int c4 = lane & 15;       // float4 column index
  const int beg = row_start[node];
  const int end = row_start[node + 1];

  float4 acc = {0.f, 0.f, 0.f, 0.f};
  int e = beg;
  // 8 rows in flight
  for (; e + 8 <= end; e += 8) {
    int ia = srcs[e + g];
    int ib = srcs[e + 4 + g];
    const float4 va = *(const float4*)&H[(size_t)ia * NF + c4 * 4];
    const float4 vb = *(const float4*)&H[(size_t)ib * NF + c4 * 4];
    acc.x += va.x + vb.x;
    acc.y += va.y + vb.y;
    acc.z += va.z + vb.z;
    acc.w += va.w + vb.w;
  }
  if (e + 4 <= end) {
    int ia = srcs[e + g];
    const float4 va = *(const float4*)&H[(size_t)ia * NF + c4 * 4];
    acc.x += va.x; acc.y += va.y; acc.z += va.z; acc.w += va.w;
    e += 4;
  }
  if (e < end) {  // masked tail (1..3 rows)
    int idx = e + g < end ? e + g : end - 1;
    float m = (e + g < end) ? 1.f : 0.f;
    int ia = srcs[idx];
    const float4 va = *(const float4*)&H[(size_t)ia * NF + c4 * 4];
    acc.x += va.x * m; acc.y += va.y * m; acc.z += va.z * m; acc.w += va.w * m;
  }

  // merge the 4 row-groups: butterfly over lane bits 4 (16) and 5 (32)
  acc.x += __shfl_xor(acc.x, 16); acc.y += __shfl_xor(acc.y, 16);
  acc.z += __shfl_xor(acc.z, 16); acc.w += __shfl_xor(acc.w, 16);
  acc.x += __shfl_xor(acc.x, 32); acc.y += __shfl_xor(acc.y, 32);
  acc.z += __shfl_xor(acc.z, 32); acc.w += __shfl_xor(acc.w, 32);

  if (g == 0) {
    const float4 b4 = *(const float4*)&bias[c4 * 4];
    float sin = si[node];
    float4 r;
    r.x = fmaf(acc.x, sin, b4.x);
    r.y = fmaf(acc.y, sin, b4.y);
    r.z = fmaf(acc.z, sin, b4.z);
    r.w = fmaf(acc.w, sin, b4.w);
    if (MODE == 0) {
      float son = so[node];
      r.x = fmaxf(r.x, 0.f) * son;
      r.y = fmaxf(r.y, 0.f) * son;
      r.z = fmaxf(r.z, 0.f) * son;
      r.w = fmaxf(r.w, 0.f) * son;
    }
    *(float4*)&out[(size_t)node * NF + c4 * 4] = r;
  }
}

// ---------------------------------------------------------------------------
extern "C" void kernel_launch(void* const* d_in, const int* in_sizes, int n_in,
                              void* d_out, int out_size, void* d_ws, size_t ws_size,
                              hipStream_t stream) {
  const float* x  = (const float*)d_in[0];
  const float* W1 = (const float*)d_in[1];
  const float* b1 = (const float*)d_in[2];
  const float* W2 = (const float*)d_in[3];
  const float* b2 = (const float*)d_in[4];
  const int* src  = (const int*)d_in[5];
  const int* dst  = (const int*)d_in[6];
  float* out = (float*)d_out;

  const int N = in_sizes[0] / NF;   // 50000
  const int E = in_sizes[5];        // 800000
  const int NB = (N + 255) / 256;   // scan blocks (196 <= 256)

  // Workspace layout (256B-aligned segments), ~33 MB total.
  char* ws = (char*)d_ws;
  size_t p = 0;
  auto alloc = [&](size_t bytes) -> void* {
    void* r = ws + p;
    p = (p + bytes + 255) & ~(size_t)255;
    return r;
  };
  int*   deg_out_i  = (int*)  alloc((size_t)N * 4);   // ws offset 0
  int*   deg_in_i   = (int*)  alloc((size_t)N * 4);   // contiguous after deg_out_i
  float* so         = (float*)alloc((size_t)N * 4);
  float* si         = (float*)alloc((size_t)N * 4);
  int*   row_start  = (int*)  alloc((size_t)(N + 1) * 4);
  int*   bsum       = (int*)  alloc((size_t)NB * 4);
  int*   lscan      = (int*)  alloc((size_t)N * 4);
  int*   ticket     = (int*)  alloc((size_t)E * 4);
  int*   sorted_src = (int*)  alloc((size_t)E * 4);
  float* h          = (float*)alloc((size_t)N * NF * 4);
  float* tbuf       = (float*)alloc((size_t)N * NF * 4);

  // 1. degrees + tickets (single memset covers both adjacent deg arrays)
  size_t degpair = (((size_t)N * 4 + 255) & ~(size_t)255) + (size_t)N * 4;
  hipMemsetAsync(deg_out_i, 0, degpair, stream);
  edge_kernel<<<(E + 255) / 256, 256, 0, stream>>>(src, dst, deg_out_i, deg_in_i, ticket, E);

  // 2. CSR row_start (+ so/si fused into scan3), atomic-free placement
  scan1_kernel<<<NB, 256, 0, stream>>>(deg_in_i, lscan, bsum, N);
  scan2_kernel<<<1, 256, 0, stream>>>(bsum, NB);
  scan3_kernel<<<NB, 256, 0, stream>>>(lscan, bsum, deg_out_i, deg_in_i,
                                       row_start, so, si, N, E);
  place_kernel<<<(E + 255) / 256, 256, 0, stream>>>(src, dst, ticket, row_start,
                                                    sorted_src, E);

  const int ggrid = (N + 63) / 64;
  const int agrid = (N + 3) / 4;

  // 3. layer 1: h = (x*so) @ W1 ; t = relu(segsum(h)*si + b1) * so
  gemm64<0><<<ggrid, 256, 0, stream>>>(x, so, W1, h, N);
  agg_kernel<0><<<agrid, 256, 0, stream>>>(h, row_start, sorted_src, si, so, b1, tbuf, N);

  // 4. layer 2: h = t @ W2 ; out = segsum(h)*si + b2
  gemm64<1><<<ggrid, 256, 0, stream>>>(tbuf, nullptr, W2, h, N);
  agg_kernel<1><<<agrid, 256, 0, stream>>>(h, row_start, sorted_src, si, nullptr, b2, out, N);
}

// Round 4
// 281.792 us; speedup vs baseline: 2.0121x; 1.0603x over previous
//
#include <hip/hip_runtime.h>

#define NF 64  // feature width (F_IN == F_LAT == F_OUT == 64)

// f32 -> bf16 round-to-nearest-even (bit trick, no NaN inputs here)
__device__ __forceinline__ unsigned short f2bf(float f) {
  unsigned int u = __float_as_uint(f);
  return (unsigned short)((u + 0x7fffu + ((u >> 16) & 1u)) >> 16);
}

// ---------------------------------------------------------------------------
// Degree histogram + dst-ticket: one thread per edge. ~20G atomic line-ops/s
// is the HW rate (measured r1/r3) -> this kernel is the structural floor
// unless atomics are removed entirely (radix sort).
__global__ __launch_bounds__(256) void edge_kernel(
    const int* __restrict__ src, const int* __restrict__ dst,
    int* __restrict__ deg_out, int* __restrict__ deg_in,
    int* __restrict__ ticket, int nE) {
  int e = blockIdx.x * blockDim.x + threadIdx.x;
  if (e >= nE) return;
  int t = atomicAdd(&deg_in[dst[e]], 1);
  ticket[e] = t;
  atomicAdd(&deg_out[src[e]], 1);
}

// ---------------------------------------------------------------------------
// Exclusive scan of deg_in -> row_start. scan1: per-block scan + block sums.
__global__ __launch_bounds__(256) void scan1_kernel(
    const int* __restrict__ deg, int* __restrict__ lscan,
    int* __restrict__ bsum, int n) {
  __shared__ int s[256];
  int tid = threadIdx.x;
  int i = blockIdx.x * 256 + tid;
  int v = (i < n) ? deg[i] : 0;
  s[tid] = v;
  __syncthreads();
  #pragma unroll
  for (int off = 1; off < 256; off <<= 1) {
    int t2 = (tid >= off) ? s[tid - off] : 0;
    __syncthreads();
    s[tid] += t2;
    __syncthreads();
  }
  if (i < n) lscan[i] = s[tid] - v;  // exclusive within block
  if (tid == 255) bsum[blockIdx.x] = s[255];
}

// scan3: block b reduces bsum[0..b) itself (NB<=256), finalizes row_start and
// the deg^{-1/2} factors (former scan2+isqrt fused in).
__global__ __launch_bounds__(256) void scan3_kernel(
    const int* __restrict__ lscan, const int* __restrict__ bsum,
    const int* __restrict__ deg_out, const int* __restrict__ deg_in,
    int* __restrict__ row_start, float* __restrict__ so, float* __restrict__ si,
    int n, int nE) {
  __shared__ int red[256];
  const int tid = threadIdx.x;
  const int b = blockIdx.x;
  red[tid] = (tid < b) ? bsum[tid] : 0;
  __syncthreads();
  #pragma unroll
  for (int s = 128; s > 0; s >>= 1) {
    if (tid < s) red[tid] += red[tid + s];
    __syncthreads();
  }
  const int off = red[0];
  const int i = b * 256 + tid;
  if (b == 0 && tid == 0) row_start[n] = nE;
  if (i < n) {
    row_start[i] = lscan[i] + off;
    int dO = deg_out[i];
    int dI = deg_in[i];
    so[i] = dO > 0 ? rsqrtf((float)dO) : 0.f;
    si[i] = dI > 0 ? rsqrtf((float)dI) : 0.f;
  }
}

// ---------------------------------------------------------------------------
// Register-blocked GEMM body: H[r][j] = sum_k T(A[r][k]) * W[k][j], bf16 out.
//   MODE 0: T = A[r][k] * so[r]   (layer-1 pre-scale)
//   MODE 1: T = A[r][k]
template <int MODE>
__device__ __forceinline__ void gemm64_body(
    const float* __restrict__ A, const float* __restrict__ so,
    const float* __restrict__ W, unsigned short* __restrict__ H,
    int n, int block) {
  __shared__ float Wl[NF * NF];       // 16 KB, row-major [k][j]
  __shared__ float Xl[NF * 68];       // 17 KB, row-major [r][k], stride 68
  const int t = threadIdx.x;

  #pragma unroll
  for (int i = 0; i < 16; ++i) Wl[t + 256 * i] = W[t + 256 * i];

  const int row0 = block * 64;
  #pragma unroll
  for (int i = 0; i < 16; ++i) {
    int idx = t + 256 * i;            // [0, 4096)
    int r = idx >> 6;
    int c = idx & 63;
    int gr = row0 + r;
    float v = 0.f;
    if (gr < n) {
      v = A[(size_t)gr * NF + c];
      if (MODE == 0) v *= so[gr];
    }
    Xl[r * 68 + c] = v;
  }
  __syncthreads();

  const int tx = t & 15;              // col group: cols tx*4..+3
  const int ty = t >> 4;              // row group: rows ty*4..+3
  float4 acc0 = {0, 0, 0, 0}, acc1 = {0, 0, 0, 0};
  float4 acc2 = {0, 0, 0, 0}, acc3 = {0, 0, 0, 0};

  #pragma unroll
  for (int k4 = 0; k4 < 16; ++k4) {
    const float4 a0 = *(const float4*)&Xl[(ty * 4 + 0) * 68 + k4 * 4];
    const float4 a1 = *(const float4*)&Xl[(ty * 4 + 1) * 68 + k4 * 4];
    const float4 a2 = *(const float4*)&Xl[(ty * 4 + 2) * 68 + k4 * 4];
    const float4 a3 = *(const float4*)&Xl[(ty * 4 + 3) * 68 + k4 * 4];
    const float4 b0 = *(const float4*)&Wl[(k4 * 4 + 0) * NF + tx * 4];
    const float4 b1 = *(const float4*)&Wl[(k4 * 4 + 1) * NF + tx * 4];
    const float4 b2 = *(const float4*)&Wl[(k4 * 4 + 2) * NF + tx * 4];
    const float4 b3 = *(const float4*)&Wl[(k4 * 4 + 3) * NF + tx * 4];

#define FMA4(ACC, AV, BV)                         \
    ACC.x = fmaf(AV, BV.x, ACC.x);                \
    ACC.y = fmaf(AV, BV.y, ACC.y);                \
    ACC.z = fmaf(AV, BV.z, ACC.z);                \
    ACC.w = fmaf(AV, BV.w, ACC.w);
    FMA4(acc0, a0.x, b0) FMA4(acc0, a0.y, b1) FMA4(acc0, a0.z, b2) FMA4(acc0, a0.w, b3)
    FMA4(acc1, a1.x, b0) FMA4(acc1, a1.y, b1) FMA4(acc1, a1.z, b2) FMA4(acc1, a1.w, b3)
    FMA4(acc2, a2.x, b0) FMA4(acc2, a2.y, b1) FMA4(acc2, a2.z, b2) FMA4(acc2, a2.w, b3)
    FMA4(acc3, a3.x, b0) FMA4(acc3, a3.y, b1) FMA4(acc3, a3.z, b2) FMA4(acc3, a3.w, b3)
#undef FMA4
  }

  const int col = tx * 4;
  #pragma unroll
  for (int i = 0; i < 4; ++i) {
    int gr = row0 + ty * 4 + i;
    if (gr >= n) continue;
    float4 v = (i == 0) ? acc0 : (i == 1) ? acc1 : (i == 2) ? acc2 : acc3;
    ushort4 o;
    o.x = f2bf(v.x); o.y = f2bf(v.y); o.z = f2bf(v.z); o.w = f2bf(v.w);
    *(ushort4*)&H[(size_t)gr * NF + col] = o;  // 8B store
  }
}

// Standalone layer-2 GEMM (MODE 1).
__global__ __launch_bounds__(256) void gemm64_k(
    const float* __restrict__ A, const float* __restrict__ W,
    unsigned short* __restrict__ H, int n) {
  gemm64_body<1>(A, nullptr, W, H, n, blockIdx.x);
}

// Fused: blocks [0,ggrid) run layer-1 GEMM (MODE 0); blocks [ggrid,..) run the
// atomic-free counting-sort placement. Both depend only on scan3; the
// scattered-store-bound place waves overlap the VALU-bound GEMM waves.
__global__ __launch_bounds__(256) void place_gemm_kernel(
    const float* __restrict__ A, const float* __restrict__ so,
    const float* __restrict__ W, unsigned short* __restrict__ H, int n, int ggrid,
    const int* __restrict__ src, const int* __restrict__ dst,
    const int* __restrict__ ticket, const int* __restrict__ row_start,
    int* __restrict__ sorted_src, int nE) {
  if ((int)blockIdx.x >= ggrid) {
    int e = (blockIdx.x - ggrid) * 256 + threadIdx.x;
    if (e < nE) sorted_src[row_start[dst[e]] + ticket[e]] = src[e];
    return;
  }
  gemm64_body<0>(A, so, W, H, n, blockIdx.x);
}

// ---------------------------------------------------------------------------
// CSR segment-sum over bf16 rows: row = 128 B = 2 cachelines. Lane group
// g = lane>>3 (8 groups) handles row srcs[e+g]; each lane loads float4 = 8
// bf16 -> ONE instruction gathers 8 full rows. f32 accumulate, butterfly
// (xor 8,16,32) merges the 8 groups.
//   MODE 0 (inter-layer): out = relu(sum*si + b) * so   (f32, feeds gemm2)
//   MODE 1 (final):       out = sum*si + b
template <int MODE>
__global__ __launch_bounds__(256) void agg_kernel(
    const unsigned short* __restrict__ H, const int* __restrict__ row_start,
    const int* __restrict__ srcs, const float* __restrict__ si,
    const float* __restrict__ so, const float* __restrict__ bias,
    float* __restrict__ out, int n) {
  int node = blockIdx.x * 4 + (threadIdx.x >> 6);
  if (node >= n) return;
  const int lane = threadIdx.x & 63;
  const int g = lane >> 3;        // row group 0..7
  const int c = lane & 7;         // 16B chunk index within row
  const int beg = row_start[node];
  const int end = row_start[node + 1];
  const float4* Hv = (const float4*)H;   // row = 8 chunks of 16B

  float acc[8] = {0, 0, 0, 0, 0, 0, 0, 0};
  int e = beg;
  for (; e + 16 <= end; e += 16) {          // 16 rows in flight
    int ia = srcs[e + g];
    int ib = srcs[e + 8 + g];
    float4 va = Hv[(size_t)ia * 8 + c];
    float4 vb = Hv[(size_t)ib * 8 + c];
    const unsigned int* pa = (const unsigned int*)&va;
    const unsigned int* pb = (const unsigned int*)&vb;
    #pragma unroll
    for (int k = 0; k < 4; ++k) {
      acc[2 * k]     += __uint_as_float(pa[k] << 16) + __uint_as_float(pb[k] << 16);
      acc[2 * k + 1] += __uint_as_float(pa[k] & 0xffff0000u) + __uint_as_float(pb[k] & 0xffff0000u);
    }
  }
  if (e + 8 <= end) {
    int ia = srcs[e + g];
    float4 va = Hv[(size_t)ia * 8 + c];
    const unsigned int* pa = (const unsigned int*)&va;
    #pragma unroll
    for (int k = 0; k < 4; ++k) {
      acc[2 * k]     += __uint_as_float(pa[k] << 16);
      acc[2 * k + 1] += __uint_as_float(pa[k] & 0xffff0000u);
    }
    e += 8;
  }
  if (e < end) {                            // masked tail, 1..7 rows
    int idx = (e + g < end) ? (e + g) : (end - 1);
    float m = (e + g < end) ? 1.f : 0.f;
    int ia = srcs[idx];
    float4 va = Hv[(size_t)ia * 8 + c];
    const unsigned int* pa = (const unsigned int*)&va;
    #pragma unroll
    for (int k = 0; k < 4; ++k) {
      acc[2 * k]     += m * __uint_as_float(pa[k] << 16);
      acc[2 * k + 1] += m * __uint_as_float(pa[k] & 0xffff0000u);
    }
  }

  // merge 8 row-groups: butterfly over lane bits 3,4,5
  #pragma unroll
  for (int d = 8; d <= 32; d <<= 1) {
    #pragma unroll
    for (int k = 0; k < 8; ++k) acc[k] += __shfl_xor(acc[k], d);
  }

  if (g == 0) {   // lanes 0..7: lane c owns features c*8 .. c*8+7
    const float sin = si[node];
    const float4 b4a = *(const float4*)&bias[c * 8];
    const float4 b4b = *(const float4*)&bias[c * 8 + 4];
    const float bb[8] = {b4a.x, b4a.y, b4a.z, b4a.w, b4b.x, b4b.y, b4b.z, b4b.w};
    float r[8];
    #pragma unroll
    for (int k = 0; k < 8; ++k) {
      float v = fmaf(acc[k], sin, bb[k]);
      if (MODE == 0) v = fmaxf(v, 0.f) * so[node];
      r[k] = v;
    }
    *(float4*)&out[(size_t)node * NF + c * 8]     = make_float4(r[0], r[1], r[2], r[3]);
    *(float4*)&out[(size_t)node * NF + c * 8 + 4] = make_float4(r[4], r[5], r[6], r[7]);
  }
}

// ---------------------------------------------------------------------------
extern "C" void kernel_launch(void* const* d_in, const int* in_sizes, int n_in,
                              void* d_out, int out_size, void* d_ws, size_t ws_size,
                              hipStream_t stream) {
  const float* x  = (const float*)d_in[0];
  const float* W1 = (const float*)d_in[1];
  const float* b1 = (const float*)d_in[2];
  const float* W2 = (const float*)d_in[3];
  const float* b2 = (const float*)d_in[4];
  const int* src  = (const int*)d_in[5];
  const int* dst  = (const int*)d_in[6];
  float* out = (float*)d_out;

  const int N = in_sizes[0] / NF;   // 50000
  const int E = in_sizes[5];        // 800000
  const int NB = (N + 255) / 256;   // scan blocks (196 <= 256)

  // Workspace layout (256B-aligned segments), ~27 MB total.
  char* ws = (char*)d_ws;
  size_t p = 0;
  auto alloc = [&](size_t bytes) -> void* {
    void* r = ws + p;
    p = (p + bytes + 255) & ~(size_t)255;
    return r;
  };
  int*   deg_out_i  = (int*)  alloc((size_t)N * 4);   // ws offset 0
  int*   deg_in_i   = (int*)  alloc((size_t)N * 4);   // contiguous after deg_out_i
  float* so         = (float*)alloc((size_t)N * 4);
  float* si         = (float*)alloc((size_t)N * 4);
  int*   row_start  = (int*)  alloc((size_t)(N + 1) * 4);
  int*   bsum       = (int*)  alloc((size_t)NB * 4);
  int*   lscan      = (int*)  alloc((size_t)N * 4);
  int*   ticket     = (int*)  alloc((size_t)E * 4);
  int*   sorted_src = (int*)  alloc((size_t)E * 4);
  unsigned short* h = (unsigned short*)alloc((size_t)N * NF * 2);  // bf16, both layers
  float* tbuf       = (float*)alloc((size_t)N * NF * 4);

  // 1. degrees + tickets (single memset covers both adjacent deg arrays)
  size_t degpair = (((size_t)N * 4 + 255) & ~(size_t)255) + (size_t)N * 4;
  hipMemsetAsync(deg_out_i, 0, degpair, stream);
  edge_kernel<<<(E + 255) / 256, 256, 0, stream>>>(src, dst, deg_out_i, deg_in_i, ticket, E);

  // 2. CSR row_start + so/si (scan2 folded into scan3)
  scan1_kernel<<<NB, 256, 0, stream>>>(deg_in_i, lscan, bsum, N);
  scan3_kernel<<<NB, 256, 0, stream>>>(lscan, bsum, deg_out_i, deg_in_i,
                                       row_start, so, si, N, E);

  const int ggrid = (N + 63) / 64;
  const int pgrid = (E + 255) / 256;
  const int agrid = (N + 3) / 4;

  // 3. fused: layer-1 GEMM (h = bf16((x*so)@W1)) + sorted_src placement
  place_gemm_kernel<<<ggrid + pgrid, 256, 0, stream>>>(
      x, so, W1, h, N, ggrid, src, dst, ticket, row_start, sorted_src, E);

  // 4. t = relu(segsum(h)*si + b1) * so
  agg_kernel<0><<<agrid, 256, 0, stream>>>(h, row_start, sorted_src, si, so, b1, tbuf, N);

  // 5. layer 2: h = bf16(t @ W2)
  gemm64_k<<<ggrid, 256, 0, stream>>>(tbuf, W2, h, N);

  // 6. out = segsum(h)*si + b2
  agg_kernel<1><<<agrid, 256, 0, stream>>>(h, row_start, sorted_src, si, nullptr, b2, out, N);
}

// Round 5
// 276.177 us; speedup vs baseline: 2.0530x; 1.0203x over previous
//
#include <hip/hip_runtime.h>

#define NF 64        // feature width
#define B_CHUNKS 32  // edge chunks (per-chunk counts fit ushort: chunk=25K)
#define RANGE 8192   // node-range size for LDS histograms (32 KB int)

// f32 -> bf16 round-to-nearest-even
__device__ __forceinline__ unsigned short f2bf(float f) {
  unsigned int u = __float_as_uint(f);
  return (unsigned short)((u + 0x7fffu + ((u >> 16) & 1u)) >> 16);
}

// ---------------------------------------------------------------------------
// Atomic-free degree computation: per-(range,chunk) LDS histograms.
// kind 0: dst -> Gin ; kind 1: src -> Gout. G[b][n] = count of key n in
// chunk b. All global traffic coalesced; LDS atomics are ~free.
__global__ __launch_bounds__(256) void hist_kernel(
    const int* __restrict__ src, const int* __restrict__ dst,
    unsigned short* __restrict__ Gout, unsigned short* __restrict__ Gin,
    int n, int nE, int R) {
  __shared__ int cnt[RANGE];
  const int rb = blockIdx.x % (R * B_CHUNKS);
  const int kind = blockIdx.x / (R * B_CHUNKS);
  const int r = rb / B_CHUNKS, b = rb % B_CHUNKS;
  const int r0 = r * RANGE;
  for (int i = threadIdx.x; i < RANGE; i += 256) cnt[i] = 0;
  __syncthreads();
  const int* keys = kind ? src : dst;
  const int chunk = (nE + B_CHUNKS - 1) / B_CHUNKS;
  const int lo = b * chunk, hi = min(lo + chunk, nE);
  for (int e = lo + threadIdx.x; e < hi; e += 256) {
    unsigned int k = (unsigned int)(keys[e] - r0);
    if (k < (unsigned int)RANGE) atomicAdd(&cnt[k], 1);
  }
  __syncthreads();
  unsigned short* G = kind ? Gout : Gin;
  for (int i = threadIdx.x; i < RANGE; i += 256) {
    int nidx = r0 + i;
    if (nidx < n) G[(size_t)b * n + nidx] = (unsigned short)cnt[i];
  }
}

// Per node: exclusive scan of Gin across chunks (in place -> per-chunk base)
// + totals -> deg_in; sum of Gout -> deg_out. Fully coalesced.
__global__ __launch_bounds__(256) void colscan_kernel(
    unsigned short* __restrict__ Gin, const unsigned short* __restrict__ Gout,
    int* __restrict__ deg_in, int* __restrict__ deg_out, int n) {
  int nidx = blockIdx.x * 256 + threadIdx.x;
  if (nidx >= n) return;
  int base = 0;
  #pragma unroll
  for (int b = 0; b < B_CHUNKS; ++b) {
    int c = Gin[(size_t)b * n + nidx];
    Gin[(size_t)b * n + nidx] = (unsigned short)base;
    base += c;
  }
  deg_in[nidx] = base;
  int s = 0;
  #pragma unroll
  for (int b = 0; b < B_CHUNKS; ++b) s += Gout[(size_t)b * n + nidx];
  deg_out[nidx] = s;
}

// ---------------------------------------------------------------------------
// Exclusive scan of deg_in -> row_start. scan1: per-block scan + block sums.
__global__ __launch_bounds__(256) void scan1_kernel(
    const int* __restrict__ deg, int* __restrict__ lscan,
    int* __restrict__ bsum, int n) {
  __shared__ int s[256];
  int tid = threadIdx.x;
  int i = blockIdx.x * 256 + tid;
  int v = (i < n) ? deg[i] : 0;
  s[tid] = v;
  __syncthreads();
  #pragma unroll
  for (int off = 1; off < 256; off <<= 1) {
    int t2 = (tid >= off) ? s[tid - off] : 0;
    __syncthreads();
    s[tid] += t2;
    __syncthreads();
  }
  if (i < n) lscan[i] = s[tid] - v;
  if (tid == 255) bsum[blockIdx.x] = s[255];
}

// scan3: block b reduces bsum[0..b) itself (NB<=256), finalizes row_start and
// deg^{-1/2} factors.
__global__ __launch_bounds__(256) void scan3_kernel(
    const int* __restrict__ lscan, const int* __restrict__ bsum,
    const int* __restrict__ deg_out, const int* __restrict__ deg_in,
    int* __restrict__ row_start, float* __restrict__ so, float* __restrict__ si,
    int n, int nE) {
  __shared__ int red[256];
  const int tid = threadIdx.x;
  const int b = blockIdx.x;
  red[tid] = (tid < b) ? bsum[tid] : 0;
  __syncthreads();
  #pragma unroll
  for (int s = 128; s > 0; s >>= 1) {
    if (tid < s) red[tid] += red[tid + s];
    __syncthreads();
  }
  const int off = red[0];
  const int i = b * 256 + tid;
  if (b == 0 && tid == 0) row_start[n] = nE;
  if (i < n) {
    row_start[i] = lscan[i] + off;
    int dO = deg_out[i];
    int dI = deg_in[i];
    so[i] = dO > 0 ? rsqrtf((float)dO) : 0.f;
    si[i] = dI > 0 ? rsqrtf((float)dI) : 0.f;
  }
}

// ---------------------------------------------------------------------------
// Register-blocked GEMM body (smem provided by caller): bf16 out.
//   MODE 0: T = A[r][k] * so[r] ; MODE 1: T = A[r][k]
template <int MODE>
__device__ __forceinline__ void gemm64_body(
    float* __restrict__ smem,
    const float* __restrict__ A, const float* __restrict__ so,
    const float* __restrict__ W, unsigned short* __restrict__ H,
    int n, int block) {
  float* Wl = smem;          // 4096 floats, row-major [k][j]
  float* Xl = smem + 4096;   // 64 rows, stride 68
  const int t = threadIdx.x;

  #pragma unroll
  for (int i = 0; i < 16; ++i) Wl[t + 256 * i] = W[t + 256 * i];

  const int row0 = block * 64;
  #pragma unroll
  for (int i = 0; i < 16; ++i) {
    int idx = t + 256 * i;
    int r = idx >> 6;
    int c = idx & 63;
    int gr = row0 + r;
    float v = 0.f;
    if (gr < n) {
      v = A[(size_t)gr * NF + c];
      if (MODE == 0) v *= so[gr];
    }
    Xl[r * 68 + c] = v;
  }
  __syncthreads();

  const int tx = t & 15;
  const int ty = t >> 4;
  float4 acc0 = {0, 0, 0, 0}, acc1 = {0, 0, 0, 0};
  float4 acc2 = {0, 0, 0, 0}, acc3 = {0, 0, 0, 0};

  #pragma unroll
  for (int k4 = 0; k4 < 16; ++k4) {
    const float4 a0 = *(const float4*)&Xl[(ty * 4 + 0) * 68 + k4 * 4];
    const float4 a1 = *(const float4*)&Xl[(ty * 4 + 1) * 68 + k4 * 4];
    const float4 a2 = *(const float4*)&Xl[(ty * 4 + 2) * 68 + k4 * 4];
    const float4 a3 = *(const float4*)&Xl[(ty * 4 + 3) * 68 + k4 * 4];
    const float4 b0 = *(const float4*)&Wl[(k4 * 4 + 0) * NF + tx * 4];
    const float4 b1 = *(const float4*)&Wl[(k4 * 4 + 1) * NF + tx * 4];
    const float4 b2 = *(const float4*)&Wl[(k4 * 4 + 2) * NF + tx * 4];
    const float4 b3 = *(const float4*)&Wl[(k4 * 4 + 3) * NF + tx * 4];

#define FMA4(ACC, AV, BV)                         \
    ACC.x = fmaf(AV, BV.x, ACC.x);                \
    ACC.y = fmaf(AV, BV.y, ACC.y);                \
    ACC.z = fmaf(AV, BV.z, ACC.z);                \
    ACC.w = fmaf(AV, BV.w, ACC.w);
    FMA4(acc0, a0.x, b0) FMA4(acc0, a0.y, b1) FMA4(acc0, a0.z, b2) FMA4(acc0, a0.w, b3)
    FMA4(acc1, a1.x, b0) FMA4(acc1, a1.y, b1) FMA4(acc1, a1.z, b2) FMA4(acc1, a1.w, b3)
    FMA4(acc2, a2.x, b0) FMA4(acc2, a2.y, b1) FMA4(acc2, a2.z, b2) FMA4(acc2, a2.w, b3)
    FMA4(acc3, a3.x, b0) FMA4(acc3, a3.y, b1) FMA4(acc3, a3.z, b2) FMA4(acc3, a3.w, b3)
#undef FMA4
  }

  const int col = tx * 4;
  #pragma unroll
  for (int i = 0; i < 4; ++i) {
    int gr = row0 + ty * 4 + i;
    if (gr >= n) continue;
    float4 v = (i == 0) ? acc0 : (i == 1) ? acc1 : (i == 2) ? acc2 : acc3;
    ushort4 o;
    o.x = f2bf(v.x); o.y = f2bf(v.y); o.z = f2bf(v.z); o.w = f2bf(v.w);
    *(ushort4*)&H[(size_t)gr * NF + col] = o;
  }
}

__global__ __launch_bounds__(256) void gemm64_k(
    const float* __restrict__ A, const float* __restrict__ W,
    unsigned short* __restrict__ H, int n) {
  __shared__ float smem[8448];
  gemm64_body<1>(smem, A, nullptr, W, H, n, blockIdx.x);
}

// Fused: blocks [0,ggrid) run layer-1 GEMM; blocks [ggrid, ggrid+R*B_CHUNKS)
// run atomic-free placement: block (r,b) rebuilds local ranks for chunk b /
// node-range r in LDS, pos = row_start[d] + Gin[b][d] + rank. Only scattered
// writes: 800K ushort stores. Shared-LDS union (gemm 33.8KB > place 32KB).
__global__ __launch_bounds__(256) void place_gemm_kernel(
    const float* __restrict__ A, const float* __restrict__ so,
    const float* __restrict__ W, unsigned short* __restrict__ H, int n, int ggrid,
    const int* __restrict__ src, const int* __restrict__ dst,
    const unsigned short* __restrict__ Gin, const int* __restrict__ row_start,
    unsigned short* __restrict__ sorted_src, int nE) {
  __shared__ float smem[8448];
  if ((int)blockIdx.x >= ggrid) {
    int* cnt = (int*)smem;
    const int rb = blockIdx.x - ggrid;
    const int r = rb / B_CHUNKS, b = rb % B_CHUNKS;
    const int r0 = r * RANGE;
    for (int i = threadIdx.x; i < RANGE; i += 256) cnt[i] = 0;
    __syncthreads();
    const int chunk = (nE + B_CHUNKS - 1) / B_CHUNKS;
    const int lo = b * chunk, hi = min(lo + chunk, nE);
    for (int e = lo + threadIdx.x; e < hi; e += 256) {
      int d = dst[e];
      unsigned int k = (unsigned int)(d - r0);
      if (k < (unsigned int)RANGE) {
        int rank = atomicAdd(&cnt[k], 1);
        int pos = row_start[d] + (int)Gin[(size_t)b * n + d] + rank;
        sorted_src[pos] = (unsigned short)src[e];
      }
    }
    return;
  }
  gemm64_body<0>(smem, A, so, W, H, n, blockIdx.x);
}

// ---------------------------------------------------------------------------
// CSR segment-sum over bf16 rows (128 B = 2 lines). Lane group g=lane>>3
// handles row srcs[e+g]; each lane loads float4 = 8 bf16 -> one instruction
// gathers 8 rows. f32 accumulate; butterfly xor 8/16/32 merges groups.
//   MODE 0: out = relu(sum*si + b) * so ; MODE 1: out = sum*si + b
template <int MODE>
__global__ __launch_bounds__(256) void agg_kernel(
    const unsigned short* __restrict__ H, const int* __restrict__ row_start,
    const unsigned short* __restrict__ srcs, const float* __restrict__ si,
    const float* __restrict__ so, const float* __restrict__ bias,
    float* __restrict__ out, int n) {
  int node = blockIdx.x * 4 + (threadIdx.x >> 6);
  if (node >= n) return;
  const int lane = threadIdx.x & 63;
  const int g = lane >> 3;
  const int c = lane & 7;
  const int beg = row_start[node];
  const int end = row_start[node + 1];
  const float4* Hv = (const float4*)H;

  float acc[8] = {0, 0, 0, 0, 0, 0, 0, 0};
  int e = beg;
  for (; e + 16 <= end; e += 16) {
    int ia = srcs[e + g];
    int ib = srcs[e + 8 + g];
    float4 va = Hv[(size_t)ia * 8 + c];
    float4 vb = Hv[(size_t)ib * 8 + c];
    const unsigned int* pa = (const unsigned int*)&va;
    const unsigned int* pb = (const unsigned int*)&vb;
    #pragma unroll
    for (int k = 0; k < 4; ++k) {
      acc[2 * k]     += __uint_as_float(pa[k] << 16) + __uint_as_float(pb[k] << 16);
      acc[2 * k + 1] += __uint_as_float(pa[k] & 0xffff0000u) + __uint_as_float(pb[k] & 0xffff0000u);
    }
  }
  if (e + 8 <= end) {
    int ia = srcs[e + g];
    float4 va = Hv[(size_t)ia * 8 + c];
    const unsigned int* pa = (const unsigned int*)&va;
    #pragma unroll
    for (int k = 0; k < 4; ++k) {
      acc[2 * k]     += __uint_as_float(pa[k] << 16);
      acc[2 * k + 1] += __uint_as_float(pa[k] & 0xffff0000u);
    }
    e += 8;
  }
  if (e < end) {
    int idx = (e + g < end) ? (e + g) : (end - 1);
    float m = (e + g < end) ? 1.f : 0.f;
    int ia = srcs[idx];
    float4 va = Hv[(size_t)ia * 8 + c];
    const unsigned int* pa = (const unsigned int*)&va;
    #pragma unroll
    for (int k = 0; k < 4; ++k) {
      acc[2 * k]     += m * __uint_as_float(pa[k] << 16);
      acc[2 * k + 1] += m * __uint_as_float(pa[k] & 0xffff0000u);
    }
  }

  #pragma unroll
  for (int d = 8; d <= 32; d <<= 1) {
    #pragma unroll
    for (int k = 0; k < 8; ++k) acc[k] += __shfl_xor(acc[k], d);
  }

  if (g == 0) {
    const float sin = si[node];
    const float4 b4a = *(const float4*)&bias[c * 8];
    const float4 b4b = *(const float4*)&bias[c * 8 + 4];
    const float bb[8] = {b4a.x, b4a.y, b4a.z, b4a.w, b4b.x, b4b.y, b4b.z, b4b.w};
    float r[8];
    #pragma unroll
    for (int k = 0; k < 8; ++k) {
      float v = fmaf(acc[k], sin, bb[k]);
      if (MODE == 0) v = fmaxf(v, 0.f) * so[node];
      r[k] = v;
    }
    *(float4*)&out[(size_t)node * NF + c * 8]     = make_float4(r[0], r[1], r[2], r[3]);
    *(float4*)&out[(size_t)node * NF + c * 8 + 4] = make_float4(r[4], r[5], r[6], r[7]);
  }
}

// ---------------------------------------------------------------------------
extern "C" void kernel_launch(void* const* d_in, const int* in_sizes, int n_in,
                              void* d_out, int out_size, void* d_ws, size_t ws_size,
                              hipStream_t stream) {
  const float* x  = (const float*)d_in[0];
  const float* W1 = (const float*)d_in[1];
  const float* b1 = (const float*)d_in[2];
  const float* W2 = (const float*)d_in[3];
  const float* b2 = (const float*)d_in[4];
  const int* src  = (const int*)d_in[5];
  const int* dst  = (const int*)d_in[6];
  float* out = (float*)d_out;

  const int N = in_sizes[0] / NF;   // 50000 (must be < 65536 for ushort ids)
  const int E = in_sizes[5];        // 800000
  const int NB = (N + 255) / 256;
  const int R  = (N + RANGE - 1) / RANGE;   // 7 node ranges

  // Workspace (~22 MB). G matrices alias tbuf (dead until agg0 writes it).
  char* ws = (char*)d_ws;
  size_t p = 0;
  auto alloc = [&](size_t bytes) -> void* {
    void* r = ws + p;
    p = (p + bytes + 255) & ~(size_t)255;
    return r;
  };
  int*   deg_out_i  = (int*)  alloc((size_t)N * 4);
  int*   deg_in_i   = (int*)  alloc((size_t)N * 4);
  float* so         = (float*)alloc((size_t)N * 4);
  float* si         = (float*)alloc((size_t)N * 4);
  int*   row_start  = (int*)  alloc((size_t)(N + 1) * 4);
  int*   bsum       = (int*)  alloc((size_t)NB * 4);
  int*   lscan      = (int*)  alloc((size_t)N * 4);
  unsigned short* sorted_u16 = (unsigned short*)alloc((size_t)E * 2);
  unsigned short* h = (unsigned short*)alloc((size_t)N * NF * 2);  // bf16
  float* tbuf       = (float*)alloc((size_t)N * NF * 4);
  unsigned short* G_in  = (unsigned short*)tbuf;                   // [B][N]
  unsigned short* G_out = G_in + (size_t)B_CHUNKS * N;             // [B][N]

  // 1. atomic-free degrees + per-chunk count matrices
  hist_kernel<<<2 * R * B_CHUNKS, 256, 0, stream>>>(src, dst, G_out, G_in, N, E, R);
  colscan_kernel<<<NB, 256, 0, stream>>>(G_in, G_out, deg_in_i, deg_out_i, N);

  // 2. row_start + so/si
  scan1_kernel<<<NB, 256, 0, stream>>>(deg_in_i, lscan, bsum, N);
  scan3_kernel<<<NB, 256, 0, stream>>>(lscan, bsum, deg_out_i, deg_in_i,
                                       row_start, so, si, N, E);

  const int ggrid = (N + 63) / 64;
  const int agrid = (N + 3) / 4;

  // 3. fused: layer-1 GEMM (h = bf16((x*so)@W1)) + atomic-free placement
  place_gemm_kernel<<<ggrid + R * B_CHUNKS, 256, 0, stream>>>(
      x, so, W1, h, N, ggrid, src, dst, G_in, row_start, sorted_u16, E);

  // 4. t = relu(segsum(h)*si + b1) * so
  agg_kernel<0><<<agrid, 256, 0, stream>>>(h, row_start, sorted_u16, si, so, b1, tbuf, N);

  // 5. layer 2: h = bf16(t @ W2)
  gemm64_k<<<ggrid, 256, 0, stream>>>(tbuf, W2, h, N);

  // 6. out = segsum(h)*si + b2
  agg_kernel<1><<<agrid, 256, 0, stream>>>(h, row_start, sorted_u16, si, nullptr, b2, out, N);
}